// Round 1
// baseline (5552.550 us; speedup 1.0000x reference)
//
#include <hip/hip_runtime.h>
#include <math.h>

// Problem constants
#define RR 512   // rnn_size
#define BB 16    // batch
#define TT 64    // time steps
#define KC 2     // context size
#define NN 256   // memory slots

__device__ __forceinline__ float sigmoidf_(float x) {
    return 1.0f / (1.0f + expf(-x));
}

__device__ __forceinline__ float wave_sum(float v) {
    #pragma unroll
    for (int off = 32; off > 0; off >>= 1) v += __shfl_xor(v, off, 64);
    return v;
}
__device__ __forceinline__ float wave_max(float v) {
    #pragma unroll
    for (int off = 32; off > 0; off >>= 1) v = fmaxf(v, __shfl_xor(v, off, 64));
    return v;
}

// ---------------------------------------------------------------------------
// Precompute pre_r[t*B+b][j] = sum_k [emb | io][k] * Wih_r[j][k] + bih[j]+bhh[j]
// A' is [1024 x 1024] (second half of each row is io[b]), Wih_r is [2048 x 1024].
// grid (32, 16): bx = col tile (2048/64), by = row tile (1024/64); 256 thr.
// ---------------------------------------------------------------------------
__global__ void k_pre(const float* __restrict__ emb, const float* __restrict__ io,
                      const float* __restrict__ Wih, const float* __restrict__ bih,
                      const float* __restrict__ bhh, float* __restrict__ pre)
{
    __shared__ float As[16][65];
    __shared__ float Bs[16][65];
    int tid = threadIdx.x;
    int row0 = blockIdx.y * 64;
    int col0 = blockIdx.x * 64;
    int ty = tid >> 4, tx = tid & 15;
    float acc[4][4] = {};
    int lr = tid >> 2;             // 0..63
    int lk4 = (tid & 3) * 4;       // 0,4,8,12
    for (int k0 = 0; k0 < 1024; k0 += 16) {
        int grow = row0 + lr;
        int b = grow & 15;
        #pragma unroll
        for (int q = 0; q < 4; ++q) {
            int k = k0 + lk4 + q;
            float v = (k < RR) ? emb[(size_t)grow * RR + k]
                               : io[(size_t)b * RR + (k - RR)];
            As[lk4 + q][lr] = v;
        }
        #pragma unroll
        for (int q = 0; q < 4; ++q) {
            int k = k0 + lk4 + q;
            Bs[lk4 + q][lr] = Wih[(size_t)(col0 + lr) * 1024 + k];
        }
        __syncthreads();
        #pragma unroll
        for (int kk = 0; kk < 16; ++kk) {
            float a[4], bbv[4];
            #pragma unroll
            for (int i = 0; i < 4; ++i) a[i] = As[kk][ty * 4 + i];
            #pragma unroll
            for (int j = 0; j < 4; ++j) bbv[j] = Bs[kk][tx * 4 + j];
            #pragma unroll
            for (int i = 0; i < 4; ++i)
                #pragma unroll
                for (int j = 0; j < 4; ++j)
                    acc[i][j] += a[i] * bbv[j];
        }
        __syncthreads();
    }
    #pragma unroll
    for (int i = 0; i < 4; ++i) {
        int grow = row0 + ty * 4 + i;
        #pragma unroll
        for (int j = 0; j < 4; ++j) {
            int gcol = col0 + tx * 4 + j;
            pre[(size_t)grow * 2048 + gcol] = acc[i][j] + bih[gcol] + bhh[gcol];
        }
    }
}

// ---------------------------------------------------------------------------
// Read-LSTM: gates[b][j] = pre[t*B+b][j] + hr_in[b] . Whh_r[j]; then gate math.
// grid 512 blocks x 256 thr. Block owns 16 (b,r) pairs (same b); wave = gate.
// ---------------------------------------------------------------------------
__global__ void k_lstm_r(const float* __restrict__ pre,
                         const float* __restrict__ Whh,
                         const float* __restrict__ hr_in,
                         float* __restrict__ hr_out,
                         float* __restrict__ cr,
                         int t)
{
    __shared__ float gsm[16][4];
    int tid = threadIdx.x;
    int wave = tid >> 6, lane = tid & 63;
    int p0 = blockIdx.x * 16;
    int b = p0 >> 9, r0 = p0 & 511;
    const float4* hr4 = (const float4*)(hr_in + (size_t)b * RR) + lane * 2;
    float4 h0 = hr4[0], h1 = hr4[1];
    const float* preb = pre + (size_t)(t * BB + b) * 2048;
    for (int pp = 0; pp < 16; ++pp) {
        int j = wave * RR + r0 + pp;
        const float4* w4 = (const float4*)(Whh + (size_t)j * RR) + lane * 2;
        float4 a0 = w4[0], a1 = w4[1];
        float acc = a0.x*h0.x + a0.y*h0.y + a0.z*h0.z + a0.w*h0.w
                  + a1.x*h1.x + a1.y*h1.y + a1.z*h1.z + a1.w*h1.w;
        acc = wave_sum(acc);
        if (lane == 0) gsm[pp][wave] = acc + preb[j];
    }
    __syncthreads();
    if (tid < 16) {
        int r = r0 + tid;
        float gi = sigmoidf_(gsm[tid][0]);
        float gf = sigmoidf_(gsm[tid][1]);
        float gg = tanhf(gsm[tid][2]);
        float go = sigmoidf_(gsm[tid][3]);
        float c = gf * cr[(size_t)b * RR + r] + gi * gg;
        cr[(size_t)b * RR + r] = c;
        hr_out[(size_t)b * RR + r] = go * tanhf(c);
    }
}

// ---------------------------------------------------------------------------
// Deferred M update (z_{t-1}, hw_{t-1}) fused with sim_t = hr_t . M rows.
// grid 256 blocks (kb*8 + nchunk) x 256 thr (4 waves x 8 rows each).
// ---------------------------------------------------------------------------
__global__ void k_upd_sim(float* __restrict__ Mw,
                          const float* __restrict__ hr,
                          const float* __restrict__ hwp,
                          const float* __restrict__ zp,
                          float* __restrict__ sim,
                          int first)
{
    int tid = threadIdx.x;
    int wave = tid >> 6, lane = tid & 63;
    int kb = blockIdx.x >> 3;
    int b = kb & 15;
    int nbase = (blockIdx.x & 7) * 32 + wave * 8;
    const float4* hr4 = (const float4*)(hr + (size_t)b * RR) + lane * 2;
    float4 h0 = hr4[0], h1 = hr4[1];
    float4 w0 = make_float4(0.f, 0.f, 0.f, 0.f), w1 = w0;
    if (!first) {
        const float4* hw4 = (const float4*)(hwp + (size_t)b * RR) + lane * 2;
        w0 = hw4[0]; w1 = hw4[1];
    }
    for (int ii = 0; ii < 8; ++ii) {
        int n = nbase + ii;
        float4* row = (float4*)(Mw + ((size_t)(kb * NN + n)) * RR) + lane * 2;
        float4 m0 = row[0], m1 = row[1];
        if (!first) {
            float zf = 1.0f - zp[kb * NN + n];
            m0.x = zf * (m0.x + w0.x); m0.y = zf * (m0.y + w0.y);
            m0.z = zf * (m0.z + w0.z); m0.w = zf * (m0.w + w0.w);
            m1.x = zf * (m1.x + w1.x); m1.y = zf * (m1.y + w1.y);
            m1.z = zf * (m1.z + w1.z); m1.w = zf * (m1.w + w1.w);
            row[0] = m0; row[1] = m1;
        }
        float acc = m0.x*h0.x + m0.y*h0.y + m0.z*h0.z + m0.w*h0.w
                  + m1.x*h1.x + m1.y*h1.y + m1.z*h1.z + m1.w*h1.w;
        acc = wave_sum(acc);
        if (lane == 0) sim[kb * NN + n] = acc;
    }
}

// ---------------------------------------------------------------------------
// z = softmax(sim[kb,:]) (redundant per block) ; m[kb, rchunk] = sum_n z*M.
// grid 256 blocks (kb*8 + rc) x 256 thr. Block with rc==0 persists z.
// ---------------------------------------------------------------------------
__global__ void k_msoft(const float* __restrict__ Mw,
                        const float* __restrict__ sim,
                        float* __restrict__ zout,
                        float* __restrict__ m)
{
    __shared__ float zsh[256];
    __shared__ float red[8];
    __shared__ float part[4][64];
    int tid = threadIdx.x;
    int kb = blockIdx.x >> 3, rc = blockIdx.x & 7;
    float s = sim[kb * NN + tid];
    float mx = wave_max(s);
    if ((tid & 63) == 0) red[tid >> 6] = mx;
    __syncthreads();
    mx = fmaxf(fmaxf(red[0], red[1]), fmaxf(red[2], red[3]));
    float e = expf(s - mx);
    float sm = wave_sum(e);
    if ((tid & 63) == 0) red[4 + (tid >> 6)] = sm;
    __syncthreads();
    sm = red[4] + red[5] + red[6] + red[7];
    float z = e / sm;
    zsh[tid] = z;
    if (rc == 0) zout[kb * NN + tid] = z;
    __syncthreads();
    int r = rc * 64 + (tid & 63);
    int ns = tid >> 6;
    float acc = 0.f;
    for (int n = ns; n < NN; n += 4)
        acc += zsh[n] * Mw[((size_t)(kb * NN + n)) * RR + r];
    part[ns][tid & 63] = acc;
    __syncthreads();
    if (tid < 64)
        m[(size_t)kb * RR + rc * 64 + tid] =
            part[0][tid] + part[1][tid] + part[2][tid] + part[3][tid];
}

// ---------------------------------------------------------------------------
// comp_pre[b][j] = cattet[b] . Wc[j] + bc[j];  cattet = [hr | m0 | m1].
// grid 32 blocks (bg*16 + jchunk) x 256 thr; cattet (8 b-rows) staged in LDS.
// ---------------------------------------------------------------------------
__global__ void k_comp(const float* __restrict__ hr,
                       const float* __restrict__ mbuf,  // [K*B][R], kb = k*16+b
                       const float* __restrict__ Wc,    // [512][1536]
                       const float* __restrict__ bc,
                       float* __restrict__ comppre)     // [16][512]
{
    __shared__ float csh[8][1540];
    int tid = threadIdx.x;
    int bg = blockIdx.x >> 4;             // 0..1
    int j0 = (blockIdx.x & 15) * 32;
    for (int idx = tid; idx < 8 * 1536; idx += 256) {
        int bl = idx / 1536, i = idx - bl * 1536;
        int b = bg * 8 + bl;
        float v;
        if (i < RR)            v = hr[(size_t)b * RR + i];
        else if (i < 2 * RR)   v = mbuf[(size_t)b * RR + (i - RR)];          // k=0
        else                   v = mbuf[(size_t)(BB + b) * RR + (i - 2*RR)]; // k=1
        csh[bl][i] = v;
    }
    __syncthreads();
    int bl = tid & 7;
    int j = j0 + (tid >> 3);
    int b = bg * 8 + bl;
    const float4* wrow = (const float4*)(Wc + (size_t)j * 1536);
    const float4* crow = (const float4*)&csh[bl][0];
    float acc = 0.f;
    #pragma unroll 4
    for (int i4 = 0; i4 < 384; ++i4) {
        float4 w = wrow[i4];
        float4 c = crow[i4];
        acc += w.x*c.x + w.y*c.y + w.z*c.z + w.w*c.w;
    }
    comppre[(size_t)b * RR + j] = acc + bc[j];
}

// ---------------------------------------------------------------------------
// Write-LSTM: comp = softmax(comppre[b,:]); gates = comp.Wih_w[j] + hw.Whh_w[j]
// + biases; gate math; store hw to state + outputs[t].
// grid 512 blocks x 256 thr, same pair mapping as k_lstm_r.
// ---------------------------------------------------------------------------
__global__ void k_lstm_w(const float* __restrict__ comppre,
                         const float* __restrict__ Wih,
                         const float* __restrict__ Whh,
                         const float* __restrict__ bih,
                         const float* __restrict__ bhh,
                         const float* __restrict__ hw_in,
                         float* __restrict__ hw_out,
                         float* __restrict__ cw,
                         float* __restrict__ outputs,
                         int t)
{
    __shared__ float csh[512];
    __shared__ float red[8];
    __shared__ float gsm[16][4];
    int tid = threadIdx.x;
    int wave = tid >> 6, lane = tid & 63;
    int p0 = blockIdx.x * 16;
    int b = p0 >> 9, r0 = p0 & 511;
    // softmax of comppre[b,:] (512), redundant per block
    float v0 = comppre[(size_t)b * RR + tid];
    float v1 = comppre[(size_t)b * RR + 256 + tid];
    float mx = wave_max(fmaxf(v0, v1));
    if (lane == 0) red[wave] = mx;
    __syncthreads();
    mx = fmaxf(fmaxf(red[0], red[1]), fmaxf(red[2], red[3]));
    float e0 = expf(v0 - mx), e1 = expf(v1 - mx);
    float sm = wave_sum(e0 + e1);
    if (lane == 0) red[4 + wave] = sm;
    __syncthreads();
    sm = red[4] + red[5] + red[6] + red[7];
    float inv = 1.0f / sm;
    csh[tid] = e0 * inv;
    csh[256 + tid] = e1 * inv;
    __syncthreads();
    const float4* hw4 = (const float4*)(hw_in + (size_t)b * RR) + lane * 2;
    float4 h0 = hw4[0], h1 = hw4[1];
    const float4* cc4 = (const float4*)csh + lane * 2;
    float4 c0 = cc4[0], c1 = cc4[1];
    for (int pp = 0; pp < 16; ++pp) {
        int j = wave * RR + r0 + pp;
        const float4* wi = (const float4*)(Wih + (size_t)j * RR) + lane * 2;
        const float4* wh = (const float4*)(Whh + (size_t)j * RR) + lane * 2;
        float4 i0 = wi[0], i1 = wi[1];
        float4 g0 = wh[0], g1 = wh[1];
        float acc = i0.x*c0.x + i0.y*c0.y + i0.z*c0.z + i0.w*c0.w
                  + i1.x*c1.x + i1.y*c1.y + i1.z*c1.z + i1.w*c1.w
                  + g0.x*h0.x + g0.y*h0.y + g0.z*h0.z + g0.w*h0.w
                  + g1.x*h1.x + g1.y*h1.y + g1.z*h1.z + g1.w*h1.w;
        acc = wave_sum(acc);
        if (lane == 0) gsm[pp][wave] = acc + bih[j] + bhh[j];
    }
    __syncthreads();
    if (tid < 16) {
        int r = r0 + tid;
        float gi = sigmoidf_(gsm[tid][0]);
        float gf = sigmoidf_(gsm[tid][1]);
        float gg = tanhf(gsm[tid][2]);
        float go = sigmoidf_(gsm[tid][3]);
        float c = gf * cw[(size_t)b * RR + r] + gi * gg;
        cw[(size_t)b * RR + r] = c;
        float h = go * tanhf(c);
        hw_out[(size_t)b * RR + r] = h;
        outputs[(size_t)t * BB * RR + (size_t)b * RR + r] = h;
    }
}

// ---------------------------------------------------------------------------
// Final deferred update with (z_63, hw_63), in place in d_out's Mf region.
// grid 8192 blocks x 128 thr (float4 per thread).
// ---------------------------------------------------------------------------
__global__ void k_final(float* __restrict__ Mw, const float* __restrict__ z,
                        const float* __restrict__ hw)
{
    int row = blockIdx.x;            // kb*256 + n
    int b = (row >> 8) & 15;
    float zf = 1.0f - z[row];
    float4* rp = (float4*)(Mw + (size_t)row * RR) + threadIdx.x;
    const float4* hp = (const float4*)(hw + (size_t)b * RR) + threadIdx.x;
    float4 m = *rp, h = *hp;
    m.x = zf * (m.x + h.x); m.y = zf * (m.y + h.y);
    m.z = zf * (m.z + h.z); m.w = zf * (m.w + h.w);
    *rp = m;
}

extern "C" void kernel_launch(void* const* d_in, const int* in_sizes, int n_in,
                              void* d_out, int out_size, void* d_ws, size_t ws_size,
                              hipStream_t stream) {
    const float* emb   = (const float*)d_in[0];
    const float* hr0   = (const float*)d_in[1];
    const float* cr0   = (const float*)d_in[2];
    const float* hw0   = (const float*)d_in[3];
    const float* cw0   = (const float*)d_in[4];
    const float* io    = (const float*)d_in[5];
    const float* M0    = (const float*)d_in[6];
    const float* Wih_r = (const float*)d_in[7];
    const float* Whh_r = (const float*)d_in[8];
    const float* bih_r = (const float*)d_in[9];
    const float* bhh_r = (const float*)d_in[10];
    const float* Wc    = (const float*)d_in[11];
    const float* bc    = (const float*)d_in[12];
    const float* Wih_w = (const float*)d_in[13];
    const float* Whh_w = (const float*)d_in[14];
    const float* bih_w = (const float*)d_in[15];
    const float* bhh_w = (const float*)d_in[16];

    float* out = (float*)d_out;
    float* outputs = out;                    // [64][16][512]
    float* hrA = out + 524288;               // hr slot
    float* crS = out + 532480;               // cr slot
    float* hwA = out + 540672;               // hw slot
    float* cwS = out + 548864;               // cw slot
    float* Mw  = out + 557056;               // Mf slot, working M

    float* ws = (float*)d_ws;
    float* pre     = ws;                     // 1024*2048
    float* sim     = ws + 2097152;           // 8192
    float* zbuf    = sim + 8192;             // 8192
    float* mbuf    = zbuf + 8192;            // 32*512
    float* comppre = mbuf + 16384;           // 8192
    float* hrB     = comppre + 8192;         // 8192
    float* hwB     = hrB + 8192;             // 8192

    // init state (double-buffer slot A = d_out) and working M
    hipMemcpyAsync(Mw,  M0,  (size_t)KC*BB*NN*RR*sizeof(float), hipMemcpyDeviceToDevice, stream);
    hipMemcpyAsync(hrA, hr0, (size_t)BB*RR*sizeof(float), hipMemcpyDeviceToDevice, stream);
    hipMemcpyAsync(crS, cr0, (size_t)BB*RR*sizeof(float), hipMemcpyDeviceToDevice, stream);
    hipMemcpyAsync(hwA, hw0, (size_t)BB*RR*sizeof(float), hipMemcpyDeviceToDevice, stream);
    hipMemcpyAsync(cwS, cw0, (size_t)BB*RR*sizeof(float), hipMemcpyDeviceToDevice, stream);

    k_pre<<<dim3(32, 16), 256, 0, stream>>>(emb, io, Wih_r, bih_r, bhh_r, pre);

    for (int t = 0; t < TT; ++t) {
        float* hr_in  = (t & 1) ? hrB : hrA;
        float* hr_out = (t & 1) ? hrA : hrB;
        float* hw_in  = (t & 1) ? hwB : hwA;
        float* hw_out = (t & 1) ? hwA : hwB;
        k_lstm_r<<<512, 256, 0, stream>>>(pre, Whh_r, hr_in, hr_out, crS, t);
        k_upd_sim<<<256, 256, 0, stream>>>(Mw, hr_out, hw_in, zbuf, sim, t == 0);
        k_msoft<<<256, 256, 0, stream>>>(Mw, sim, zbuf, mbuf);
        k_comp<<<32, 256, 0, stream>>>(hr_out, mbuf, Wc, bc, comppre);
        k_lstm_w<<<512, 256, 0, stream>>>(comppre, Wih_w, Whh_w, bih_w, bhh_w,
                                          hw_in, hw_out, cwS, outputs, t);
    }
    // apply the deferred step-63 update; hw_63 lives in slot A (t=63 odd)
    k_final<<<8192, 128, 0, stream>>>(Mw, zbuf, hwA);
}